// Round 14
// baseline (99.422 us; speedup 1.0000x reference)
//
#include <hip/hip_runtime.h>

#define NN  16384
#define NE  524288
#define D   128
#define GEMMB 512
#define FILLB 256

// ws layout (bytes); total ~52 MB (ws evidenced ~260 MB)
#define OFF_BM   0u          // uint[16384*512] = 32 MB adjacency bitmap bit(dst,src)
#define OFF_CNT  33554432u   // int[16384] = 64 KB unique in-degree
#define OFF_SLAB 33619968u   // u16[16384*128] = 4 MB deduped src ids per dst
#define OFF_Y    37814272u   // float[16384*128] = 8 MB   y = x @ W^T
#define OFF_Z    46202880u   // float[16384*128] = 8 MB   z = x @ B^T
#define NZ4      2101248u    // uint4 count: (32 MB + 64 KB) / 16 = 513*256*16 exactly

typedef __bf16 bf16x4 __attribute__((ext_vector_type(4)));
typedef __bf16 bf16x8 __attribute__((ext_vector_type(8)));
typedef float  f32x4  __attribute__((ext_vector_type(4)));
typedef unsigned short u16;

// Zero bm + cnt (contiguous): 513 blocks x 256 thr x 16 uint4 = 33,619,968 B exactly.
__global__ __launch_bounds__(256) void zero_k(uint4* __restrict__ p) {
  int i = blockIdx.x * 256 + threadIdx.x;        // 0..131327
#pragma unroll
  for (int u = 0; u < 16; ++u)
    p[(size_t)u * 131328 + i] = uint4{0, 0, 0, 0};
}

// K1: blocks [0,512): [y|z] = x @ [W|B]^T via bf16 MFMA (K=128, 32 rows/block).
//     blocks [512,768): edge pass -> dedup at insert: atomicOr(bm) old-test picks
//     one owner per (dst,src); owner appends src to slab[dst] and bumps cnt[dst].
__global__ __launch_bounds__(256, 2) void k1(const float* __restrict__ x,
                                             const int* __restrict__ ei,
                                             const float* __restrict__ W,
                                             const float* __restrict__ Bm,
                                             float* __restrict__ y,
                                             float* __restrict__ z,
                                             unsigned* __restrict__ bm,
                                             int* __restrict__ cnt,
                                             u16* __restrict__ slab) {
  __shared__ __bf16 sA[32][40];    // 2.5 KB
  __shared__ __bf16 sB[256][40];   // 20 KB  (rows 0..127 = W, 128..255 = B)
  __shared__ int s_any;
  int b = blockIdx.x, t = threadIdx.x;

  if (b < GEMMB) {
    int l = t & 63, wid = t >> 6;
    int g = l >> 4, ln = l & 15;
    int mh = wid & 1, nh = wid >> 1;
    int row0 = b * 32;
    f32x4 acc[8];
#pragma unroll
    for (int nb = 0; nb < 8; ++nb) acc[nb] = f32x4{0.f, 0.f, 0.f, 0.f};

    for (int kc = 0; kc < 4; ++kc) {
      int kb = kc * 32;
      __syncthreads();
      {                                   // A: 32 rows x 32 k from x
        int rr = t >> 3, q = t & 7;
        float4 v = *(const float4*)&x[(size_t)(row0 + rr) * D + kb + q * 4];
        bf16x4 w = {(__bf16)v.x, (__bf16)v.y, (__bf16)v.z, (__bf16)v.w};
        *(bf16x4*)&sA[rr][q * 4] = w;
      }
#pragma unroll
      for (int u = 0; u < 8; ++u) {       // B': 256 rows (W;B) x 32 k
        int f = u * 256 + t;
        int rr = f >> 3, q = f & 7;
        const float* Bp = (rr < 128) ? &W[(size_t)rr * D] : &Bm[(size_t)(rr - 128) * D];
        float4 v = *(const float4*)&Bp[kb + q * 4];
        bf16x4 w = {(__bf16)v.x, (__bf16)v.y, (__bf16)v.z, (__bf16)v.w};
        *(bf16x4*)&sB[rr][q * 4] = w;
      }
      __syncthreads();
      bf16x8 afr = *(const bf16x8*)&sA[mh * 16 + ln][g * 8];
#pragma unroll
      for (int nb = 0; nb < 8; ++nb) {
        bf16x8 bfr = *(const bf16x8*)&sB[nh * 128 + nb * 16 + ln][g * 8];
        acc[nb] = __builtin_amdgcn_mfma_f32_16x16x32_bf16(afr, bfr, acc[nb], 0, 0, 0);
      }
    }
    float* dstm = (nh == 0) ? y : z;   // C/D: col = ln, row = g*4+i [verified r4-r9]
#pragma unroll
    for (int nb = 0; nb < 8; ++nb)
#pragma unroll
      for (int i = 0; i < 4; ++i)
        dstm[(size_t)(row0 + mh * 16 + g * 4 + i) * D + nb * 16 + ln] = acc[nb][i];
  } else {
    // edge pass: per-block width detect (int64 => odd int32 words all zero)
    if (t == 0) s_any = 0;
    __syncthreads();
    int base = (b - GEMMB) * 2048;
    int any = 0;
#pragma unroll
    for (int u = 0; u < 8; ++u) any |= ei[2 * (base + u * 256 + t) + 1];
    if (any) atomicOr(&s_any, 1);
    __syncthreads();
    int is32 = s_any;
#pragma unroll
    for (int u = 0; u < 8; ++u) {
      int i = base + u * 256 + t;
      int s = is32 ? ei[i] : ei[2 * i];
      int d = is32 ? ei[NE + i] : ei[2 * (NE + i)];
      unsigned bit = 1u << (s & 31);
      unsigned old = atomicOr(&bm[((size_t)d << 9) + (s >> 5)], bit);
      if (!(old & bit)) {                 // owner of (d,s): append deduped
        int slot = atomicAdd(&cnt[d], 1);
        if (slot < 128) slab[((size_t)d << 7) + slot] = (u16)s;
      }
    }
  }
}

// K2: out[row] = (1/max(deg,1)) * sum_{slab srcs} y[src] + z[row].
// No dedup, no scan: slab is already unique. One row per 32-lane group.
#define RPB 8
__global__ __launch_bounds__(256) void gather_k(const int* __restrict__ cnt,
                                                const u16* __restrict__ slab,
                                                const float* __restrict__ y,
                                                const float* __restrict__ z,
                                                float* __restrict__ out) {
  __shared__ u16 s_col[RPB][128];   // 2 KB
  int t = threadIdx.x, lane = t & 31, r = t >> 5;
  int row = blockIdx.x * RPB + r;
  int k = cnt[row];
  if (k > 128) k = 128;
  const u16* srow = slab + ((size_t)row << 7);
  for (int j = lane; j < k; j += 32) s_col[r][j] = srow[j];
  float dinv = 1.0f / (float)(k > 0 ? k : 1);

  float4 a[8];
#pragma unroll
  for (int u = 0; u < 8; ++u) a[u] = float4{0.f, 0.f, 0.f, 0.f};
  const float* yl = y + lane * 4;
#define FMA4(aa, vv) { aa.x += vv.x; aa.y += vv.y; aa.z += vv.z; aa.w += vv.w; }
  int j = 0;
  for (; j + 8 <= k; j += 8) {
    float4 v[8];
#pragma unroll
    for (int u = 0; u < 8; ++u)
      v[u] = *(const float4*)(yl + (size_t)s_col[r][j + u] * D);
#pragma unroll
    for (int u = 0; u < 8; ++u) FMA4(a[u], v[u])
  }
  for (; j < k; ++j) {
    float4 v0 = *(const float4*)(yl + (size_t)s_col[r][j] * D);
    FMA4(a[0], v0)
  }
#undef FMA4
#pragma unroll
  for (int u = 4; u < 8; ++u) {
    a[u - 4].x += a[u].x; a[u - 4].y += a[u].y;
    a[u - 4].z += a[u].z; a[u - 4].w += a[u].w;
  }
  float4 zv = *(const float4*)(z + (size_t)row * D + lane * 4);
  float4 o;
  o.x = (a[0].x + a[1].x + a[2].x + a[3].x) * dinv + zv.x;
  o.y = (a[0].y + a[1].y + a[2].y + a[3].y) * dinv + zv.y;
  o.z = (a[0].z + a[1].z + a[2].z + a[3].z) * dinv + zv.z;
  o.w = (a[0].w + a[1].w + a[2].w + a[3].w) * dinv + zv.w;
  *(float4*)(out + (size_t)row * D + lane * 4) = o;
}

extern "C" void kernel_launch(void* const* d_in, const int* in_sizes, int n_in,
                              void* d_out, int out_size, void* d_ws, size_t ws_size,
                              hipStream_t stream) {
  const float* x = (const float*)d_in[0];
  const int* ei = (const int*)d_in[1];
  const float* W = (const float*)d_in[2];
  const float* Bm = (const float*)d_in[3];
  float* out = (float*)d_out;
  char* ws = (char*)d_ws;
  unsigned* bm = (unsigned*)(ws + OFF_BM);
  int* cnt = (int*)(ws + OFF_CNT);
  u16* slab = (u16*)(ws + OFF_SLAB);
  float* y = (float*)(ws + OFF_Y);
  float* z = (float*)(ws + OFF_Z);

  zero_k<<<513, 256, 0, stream>>>((uint4*)ws);   // bm + cnt contiguous
  k1<<<GEMMB + FILLB, 256, 0, stream>>>(x, ei, W, Bm, y, z, bm, cnt, slab);
  gather_k<<<NN / RPB, 256, 0, stream>>>(cnt, slab, y, z, out);
}

// Round 15
// 72.379 us; speedup vs baseline: 1.3736x; 1.3736x over previous
//
#include <hip/hip_runtime.h>

#define NN  16384
#define NE  524288
#define D   128
#define CAP 128     // raw in-degree max ~63 (Poisson 32 over 16384 draws)
#define GEMMB 512
#define FILLB 256

// ws layout (bytes); total 20.6 MB (ws evidenced ~260 MB)
#define OFF_CNT  0u          // int[16384] raw in-degree (dups included)
#define OFF_SLAB 65536u      // u16[16384*128] = 4 MB src ids per dst (dups included)
#define OFF_Y    4259840u    // float[16384*128] = 8 MB   y = x @ W^T
#define OFF_Z    12648448u   // float[16384*128] = 8 MB   z = x @ B^T

typedef __bf16 bf16x4 __attribute__((ext_vector_type(4)));
typedef __bf16 bf16x8 __attribute__((ext_vector_type(8)));
typedef float  f32x4  __attribute__((ext_vector_type(4)));
typedef unsigned short u16;

// Zero cnt: 64 KB = 4096 int4, 16 blocks x 256 threads.
__global__ __launch_bounds__(256) void zero_k(int4* __restrict__ p) {
  p[blockIdx.x * 256 + threadIdx.x] = int4{0, 0, 0, 0};
}

// K1: blocks [0,512): [y|z] = x @ [W|B]^T via bf16 MFMA (K=128, 32 rows/block).
//     blocks [512,768): edge append (dups kept). Three ILP phases so the 8
//     atomicAdd returns are concurrently in flight (r14 lesson: a dependent
//     atomic-return chain costs ~2 orders of magnitude more than in-flight).
__global__ __launch_bounds__(256, 2) void k1(const float* __restrict__ x,
                                             const int* __restrict__ ei,
                                             const float* __restrict__ W,
                                             const float* __restrict__ Bm,
                                             float* __restrict__ y,
                                             float* __restrict__ z,
                                             int* __restrict__ cnt,
                                             u16* __restrict__ slab) {
  __shared__ __bf16 sA[32][40];    // 2.5 KB
  __shared__ __bf16 sB[256][40];   // 20 KB  (rows 0..127 = W, 128..255 = B)
  __shared__ int s_any;
  int b = blockIdx.x, t = threadIdx.x;

  if (b < GEMMB) {
    int l = t & 63, wid = t >> 6;
    int g = l >> 4, ln = l & 15;
    int mh = wid & 1, nh = wid >> 1;
    int row0 = b * 32;
    f32x4 acc[8];
#pragma unroll
    for (int nb = 0; nb < 8; ++nb) acc[nb] = f32x4{0.f, 0.f, 0.f, 0.f};

    for (int kc = 0; kc < 4; ++kc) {
      int kb = kc * 32;
      __syncthreads();
      {                                   // A: 32 rows x 32 k from x
        int rr = t >> 3, q = t & 7;
        float4 v = *(const float4*)&x[(size_t)(row0 + rr) * D + kb + q * 4];
        bf16x4 w = {(__bf16)v.x, (__bf16)v.y, (__bf16)v.z, (__bf16)v.w};
        *(bf16x4*)&sA[rr][q * 4] = w;
      }
#pragma unroll
      for (int u = 0; u < 8; ++u) {       // B': 256 rows (W;B) x 32 k
        int f = u * 256 + t;
        int rr = f >> 3, q = f & 7;
        const float* Bp = (rr < 128) ? &W[(size_t)rr * D] : &Bm[(size_t)(rr - 128) * D];
        float4 v = *(const float4*)&Bp[kb + q * 4];
        bf16x4 w = {(__bf16)v.x, (__bf16)v.y, (__bf16)v.z, (__bf16)v.w};
        *(bf16x4*)&sB[rr][q * 4] = w;
      }
      __syncthreads();
      bf16x8 afr = *(const bf16x8*)&sA[mh * 16 + ln][g * 8];
#pragma unroll
      for (int nb = 0; nb < 8; ++nb) {
        bf16x8 bfr = *(const bf16x8*)&sB[nh * 128 + nb * 16 + ln][g * 8];
        acc[nb] = __builtin_amdgcn_mfma_f32_16x16x32_bf16(afr, bfr, acc[nb], 0, 0, 0);
      }
    }
    float* dstm = (nh == 0) ? y : z;   // C/D: col = ln, row = g*4+i [verified r4-r9]
#pragma unroll
    for (int nb = 0; nb < 8; ++nb)
#pragma unroll
      for (int i = 0; i < 4; ++i)
        dstm[(size_t)(row0 + mh * 16 + g * 4 + i) * D + nb * 16 + ln] = acc[nb][i];
  } else {
    // edge pass: per-block width detect (int64 => odd int32 words all zero)
    if (t == 0) s_any = 0;
    __syncthreads();
    int base = (b - GEMMB) * 2048;
    int any = 0;
#pragma unroll
    for (int u = 0; u < 8; ++u) any |= ei[2 * (base + u * 256 + t) + 1];
    if (any) atomicOr(&s_any, 1);
    __syncthreads();
    int is32 = s_any;
    int s_[8], d_[8], slot_[8];
#pragma unroll
    for (int u = 0; u < 8; ++u) {        // phase 1: load all
      int i = base + u * 256 + t;
      s_[u] = is32 ? ei[i] : ei[2 * i];
      d_[u] = is32 ? ei[NE + i] : ei[2 * (NE + i)];
    }
#pragma unroll
    for (int u = 0; u < 8; ++u)          // phase 2: all atomics in flight
      slot_[u] = atomicAdd(&cnt[d_[u]], 1);
#pragma unroll
    for (int u = 0; u < 8; ++u)          // phase 3: stores
      if (slot_[u] < CAP) slab[((size_t)d_[u] << 7) + slot_[u]] = (u16)s_[u];
  }
}

// K2: out[row] = (1/max(uniq,1)) * sum_{unique src} y[src] + z[row].
// One row per 32-lane group; dedup via 2 KB LDS bitmap + atomicOr old-test
// (LDS-latency, intra-wave, no barriers). Keep-flag in bit 15 (ids are 14-bit).
#define RPB 8
__global__ __launch_bounds__(256) void gather_k(const int* __restrict__ cnt,
                                                const u16* __restrict__ slab,
                                                const float* __restrict__ y,
                                                const float* __restrict__ z,
                                                float* __restrict__ out) {
  __shared__ u16 s_col[RPB][CAP];        // 2 KB
  __shared__ unsigned s_bm[RPB][512];    // 16 KB
  int t = threadIdx.x, lane = t & 31, r = t >> 5;
  int row = blockIdx.x * RPB + r;
  int k = cnt[row];
  if (k > CAP) k = CAP;
  const u16* srow = slab + ((size_t)row << 7);
  for (int j = lane; j < k; j += 32) s_col[r][j] = srow[j];
#pragma unroll
  for (int u = 0; u < 16; ++u) s_bm[r][u * 32 + lane] = 0u;

  int lu = 0;
  for (int j = lane; j < k; j += 32) {
    unsigned c = s_col[r][j];
    unsigned bit = 1u << (c & 31);
    unsigned old = atomicOr(&s_bm[r][c >> 5], bit);
    int kp = (old & bit) ? 0 : 1;
    s_col[r][j] = (u16)(c | (kp << 15));
    lu += kp;
  }
#pragma unroll
  for (int off = 16; off; off >>= 1) lu += __shfl_xor(lu, off);
  float dinv = 1.0f / (float)(lu > 0 ? lu : 1);

  float4 a[8];
#pragma unroll
  for (int u = 0; u < 8; ++u) a[u] = float4{0.f, 0.f, 0.f, 0.f};
  const float* yl = y + lane * 4;
#define FMA4(aa, vv, ff) { aa.x += ff*vv.x; aa.y += ff*vv.y; aa.z += ff*vv.z; aa.w += ff*vv.w; }
  int j = 0;
  for (; j + 8 <= k; j += 8) {
    float f[8];
    float4 v[8];
#pragma unroll
    for (int u = 0; u < 8; ++u) {
      int cc = s_col[r][j + u];
      f[u] = (cc >> 15) ? 1.0f : 0.0f;
      v[u] = *(const float4*)(yl + (size_t)(cc & 0x3FFF) * D);
    }
#pragma unroll
    for (int u = 0; u < 8; ++u) FMA4(a[u], v[u], f[u])
  }
  for (; j < k; ++j) {
    int cc = s_col[r][j];
    float f0 = (cc >> 15) ? 1.0f : 0.0f;
    float4 v0 = *(const float4*)(yl + (size_t)(cc & 0x3FFF) * D);
    FMA4(a[0], v0, f0)
  }
#undef FMA4
#pragma unroll
  for (int u = 4; u < 8; ++u) {
    a[u - 4].x += a[u].x; a[u - 4].y += a[u].y;
    a[u - 4].z += a[u].z; a[u - 4].w += a[u].w;
  }
  float4 zv = *(const float4*)(z + (size_t)row * D + lane * 4);
  float4 o;
  o.x = (a[0].x + a[1].x + a[2].x + a[3].x) * dinv + zv.x;
  o.y = (a[0].y + a[1].y + a[2].y + a[3].y) * dinv + zv.y;
  o.z = (a[0].z + a[1].z + a[2].z + a[3].z) * dinv + zv.z;
  o.w = (a[0].w + a[1].w + a[2].w + a[3].w) * dinv + zv.w;
  *(float4*)(out + (size_t)row * D + lane * 4) = o;
}

extern "C" void kernel_launch(void* const* d_in, const int* in_sizes, int n_in,
                              void* d_out, int out_size, void* d_ws, size_t ws_size,
                              hipStream_t stream) {
  const float* x = (const float*)d_in[0];
  const int* ei = (const int*)d_in[1];
  const float* W = (const float*)d_in[2];
  const float* Bm = (const float*)d_in[3];
  float* out = (float*)d_out;
  char* ws = (char*)d_ws;
  int* cnt = (int*)(ws + OFF_CNT);
  u16* slab = (u16*)(ws + OFF_SLAB);
  float* y = (float*)(ws + OFF_Y);
  float* z = (float*)(ws + OFF_Z);

  zero_k<<<16, 256, 0, stream>>>((int4*)ws);               // cnt only, 64 KB
  k1<<<GEMMB + FILLB, 256, 0, stream>>>(x, ei, W, Bm, y, z, cnt, slab);
  gather_k<<<NN / RPB, 256, 0, stream>>>(cnt, slab, y, z, out);
}

// Round 16
// 61.811 us; speedup vs baseline: 1.6085x; 1.1710x over previous
//
#include <hip/hip_runtime.h>

#define NN  16384
#define NE  524288
#define D   128
#define CAP 128     // raw in-degree max ~63 (Poisson 32 over 16384 draws)
#define GEMMB 512
#define FILLB 256

// ws layout (bytes); total 16.6 MB (ws evidenced ~260 MB)
#define OFF_CNT  0u          // int[16384] raw in-degree (dups included)
#define OFF_SLAB 65536u      // u16[16384*128] = 4 MB src ids per dst (dups included)
#define OFF_Y    4259840u    // __bf16[16384*128] = 4 MB   y = x @ W^T  (bf16!)
#define OFF_Z    8454144u    // float[16384*128] = 8 MB    z = x @ B^T

typedef __bf16 bf16x4 __attribute__((ext_vector_type(4)));
typedef __bf16 bf16x8 __attribute__((ext_vector_type(8)));
typedef float  f32x4  __attribute__((ext_vector_type(4)));
typedef unsigned short u16;

// Zero cnt: 64 KB = 4096 int4, 16 blocks x 256 threads.
__global__ __launch_bounds__(256) void zero_k(int4* __restrict__ p) {
  p[blockIdx.x * 256 + threadIdx.x] = int4{0, 0, 0, 0};
}

// K1: blocks [0,512): y(bf16) and z(f32) = x @ [W|B]^T via bf16 MFMA.
//     blocks [512,768): edge append (dups kept), 3-phase ILP atomics (r14 lesson).
__global__ __launch_bounds__(256, 2) void k1(const float* __restrict__ x,
                                             const int* __restrict__ ei,
                                             const float* __restrict__ W,
                                             const float* __restrict__ Bm,
                                             __bf16* __restrict__ y,
                                             float* __restrict__ z,
                                             int* __restrict__ cnt,
                                             u16* __restrict__ slab) {
  __shared__ __bf16 sA[32][40];    // 2.5 KB
  __shared__ __bf16 sB[256][40];   // 20 KB  (rows 0..127 = W, 128..255 = B)
  __shared__ int s_any;
  int b = blockIdx.x, t = threadIdx.x;

  if (b < GEMMB) {
    int l = t & 63, wid = t >> 6;
    int g = l >> 4, ln = l & 15;
    int mh = wid & 1, nh = wid >> 1;
    int row0 = b * 32;
    f32x4 acc[8];
#pragma unroll
    for (int nb = 0; nb < 8; ++nb) acc[nb] = f32x4{0.f, 0.f, 0.f, 0.f};

    for (int kc = 0; kc < 4; ++kc) {
      int kb = kc * 32;
      __syncthreads();
      {                                   // A: 32 rows x 32 k from x
        int rr = t >> 3, q = t & 7;
        float4 v = *(const float4*)&x[(size_t)(row0 + rr) * D + kb + q * 4];
        bf16x4 w = {(__bf16)v.x, (__bf16)v.y, (__bf16)v.z, (__bf16)v.w};
        *(bf16x4*)&sA[rr][q * 4] = w;
      }
#pragma unroll
      for (int u = 0; u < 8; ++u) {       // B': 256 rows (W;B) x 32 k
        int f = u * 256 + t;
        int rr = f >> 3, q = f & 7;
        const float* Bp = (rr < 128) ? &W[(size_t)rr * D] : &Bm[(size_t)(rr - 128) * D];
        float4 v = *(const float4*)&Bp[kb + q * 4];
        bf16x4 w = {(__bf16)v.x, (__bf16)v.y, (__bf16)v.z, (__bf16)v.w};
        *(bf16x4*)&sB[rr][q * 4] = w;
      }
      __syncthreads();
      bf16x8 afr = *(const bf16x8*)&sA[mh * 16 + ln][g * 8];
#pragma unroll
      for (int nb = 0; nb < 8; ++nb) {
        bf16x8 bfr = *(const bf16x8*)&sB[nh * 128 + nb * 16 + ln][g * 8];
        acc[nb] = __builtin_amdgcn_mfma_f32_16x16x32_bf16(afr, bfr, acc[nb], 0, 0, 0);
      }
    }
    // C/D: col = ln, row = g*4+i [verified r4-r9]; nh=0 -> y (bf16), nh=1 -> z (f32)
    if (nh == 0) {
#pragma unroll
      for (int nb = 0; nb < 8; ++nb)
#pragma unroll
        for (int i = 0; i < 4; ++i)
          y[(size_t)(row0 + mh * 16 + g * 4 + i) * D + nb * 16 + ln] = (__bf16)acc[nb][i];
    } else {
#pragma unroll
      for (int nb = 0; nb < 8; ++nb)
#pragma unroll
        for (int i = 0; i < 4; ++i)
          z[(size_t)(row0 + mh * 16 + g * 4 + i) * D + nb * 16 + ln] = acc[nb][i];
    }
  } else {
    // edge pass: per-block width detect (int64 => odd int32 words all zero)
    if (t == 0) s_any = 0;
    __syncthreads();
    int base = (b - GEMMB) * 2048;
    int any = 0;
#pragma unroll
    for (int u = 0; u < 8; ++u) any |= ei[2 * (base + u * 256 + t) + 1];
    if (any) atomicOr(&s_any, 1);
    __syncthreads();
    int is32 = s_any;
    int s_[8], d_[8], slot_[8];
#pragma unroll
    for (int u = 0; u < 8; ++u) {        // phase 1: load all
      int i = base + u * 256 + t;
      s_[u] = is32 ? ei[i] : ei[2 * i];
      d_[u] = is32 ? ei[NE + i] : ei[2 * (NE + i)];
    }
#pragma unroll
    for (int u = 0; u < 8; ++u)          // phase 2: all atomics in flight
      slot_[u] = atomicAdd(&cnt[d_[u]], 1);
#pragma unroll
    for (int u = 0; u < 8; ++u)          // phase 3: stores
      if (slot_[u] < CAP) slab[((size_t)d_[u] << 7) + slot_[u]] = (u16)s_[u];
  }
}

// K2: out[row] = (1/max(uniq,1)) * sum_{unique src} y_bf16[src] + z[row].
// One row per 32-lane group (lane = 4 features = 8 B bf16 load).
// Dedup via 2 KB LDS bitmap + atomicOr old-test; keep-flag in bit 15.
#define RPB 8
__global__ __launch_bounds__(256) void gather_k(const int* __restrict__ cnt,
                                                const u16* __restrict__ slab,
                                                const u16* __restrict__ y,
                                                const float* __restrict__ z,
                                                float* __restrict__ out) {
  __shared__ u16 s_col[RPB][CAP];        // 2 KB
  __shared__ unsigned s_bm[RPB][512];    // 16 KB
  int t = threadIdx.x, lane = t & 31, r = t >> 5;
  int row = blockIdx.x * RPB + r;
  int k = cnt[row];
  if (k > CAP) k = CAP;
  const u16* srow = slab + ((size_t)row << 7);
  for (int j = lane; j < k; j += 32) s_col[r][j] = srow[j];
#pragma unroll
  for (int u = 0; u < 16; ++u) s_bm[r][u * 32 + lane] = 0u;

  int lu = 0;
  for (int j = lane; j < k; j += 32) {
    unsigned c = s_col[r][j];
    unsigned bit = 1u << (c & 31);
    unsigned old = atomicOr(&s_bm[r][c >> 5], bit);
    int kp = (old & bit) ? 0 : 1;
    s_col[r][j] = (u16)(c | (kp << 15));
    lu += kp;
  }
#pragma unroll
  for (int off = 16; off; off >>= 1) lu += __shfl_xor(lu, off);
  float dinv = 1.0f / (float)(lu > 0 ? lu : 1);

  float4 a[8];
#pragma unroll
  for (int u = 0; u < 8; ++u) a[u] = float4{0.f, 0.f, 0.f, 0.f};
  const u16* yl = y + lane * 4;          // 4 bf16 features per lane
#define ACCB(aa, vv, ff)                                                  \
  { aa.x += ff * __uint_as_float((vv).x << 16);                           \
    aa.y += ff * __uint_as_float((vv).x & 0xffff0000u);                   \
    aa.z += ff * __uint_as_float((vv).y << 16);                           \
    aa.w += ff * __uint_as_float((vv).y & 0xffff0000u); }
  int j = 0;
  for (; j + 8 <= k; j += 8) {
    float f[8];
    uint2 v[8];
#pragma unroll
    for (int u = 0; u < 8; ++u) {
      int cc = s_col[r][j + u];
      f[u] = (cc >> 15) ? 1.0f : 0.0f;
      v[u] = *(const uint2*)(yl + (size_t)(cc & 0x3FFF) * D);
    }
#pragma unroll
    for (int u = 0; u < 8; ++u) ACCB(a[u], v[u], f[u])
  }
  for (; j < k; ++j) {
    int cc = s_col[r][j];
    float f0 = (cc >> 15) ? 1.0f : 0.0f;
    uint2 v0 = *(const uint2*)(yl + (size_t)(cc & 0x3FFF) * D);
    ACCB(a[0], v0, f0)
  }
#undef ACCB
#pragma unroll
  for (int u = 4; u < 8; ++u) {
    a[u - 4].x += a[u].x; a[u - 4].y += a[u].y;
    a[u - 4].z += a[u].z; a[u - 4].w += a[u].w;
  }
  float4 zv = *(const float4*)(z + (size_t)row * D + lane * 4);
  float4 o;
  o.x = (a[0].x + a[1].x + a[2].x + a[3].x) * dinv + zv.x;
  o.y = (a[0].y + a[1].y + a[2].y + a[3].y) * dinv + zv.y;
  o.z = (a[0].z + a[1].z + a[2].z + a[3].z) * dinv + zv.z;
  o.w = (a[0].w + a[1].w + a[2].w + a[3].w) * dinv + zv.w;
  *(float4*)(out + (size_t)row * D + lane * 4) = o;
}

extern "C" void kernel_launch(void* const* d_in, const int* in_sizes, int n_in,
                              void* d_out, int out_size, void* d_ws, size_t ws_size,
                              hipStream_t stream) {
  const float* x = (const float*)d_in[0];
  const int* ei = (const int*)d_in[1];
  const float* W = (const float*)d_in[2];
  const float* Bm = (const float*)d_in[3];
  float* out = (float*)d_out;
  char* ws = (char*)d_ws;
  int* cnt = (int*)(ws + OFF_CNT);
  u16* slab = (u16*)(ws + OFF_SLAB);
  __bf16* y = (__bf16*)(ws + OFF_Y);
  float* z = (float*)(ws + OFF_Z);

  zero_k<<<16, 256, 0, stream>>>((int4*)ws);               // cnt only, 64 KB
  k1<<<GEMMB + FILLB, 256, 0, stream>>>(x, ei, W, Bm, y, z, cnt, slab);
  gather_k<<<NN / RPB, 256, 0, stream>>>(cnt, slab, (const u16*)y, z, out);
}

// Round 17
// 59.006 us; speedup vs baseline: 1.6850x; 1.0475x over previous
//
#include <hip/hip_runtime.h>

#define NN  16384
#define NE  524288
#define D   128
#define CAP 128     // raw in-degree max ~63 (Poisson 32 over 16384 draws)
#define GEMMB 512
#define FILLB 256

// ws layout (bytes); total 16.6 MB (ws evidenced ~260 MB)
#define OFF_CNT  0u          // int[16384] raw in-degree (dups included)
#define OFF_SLAB 65536u      // u16[16384*128] = 4 MB src ids per dst (dups included)
#define OFF_Y    4259840u    // __bf16[16384*128] = 4 MB   y = x @ W^T  (bf16)
#define OFF_Z    8454144u    // float[16384*128] = 8 MB    z = x @ B^T

typedef __bf16 bf16x4 __attribute__((ext_vector_type(4)));
typedef __bf16 bf16x8 __attribute__((ext_vector_type(8)));
typedef float  f32x4  __attribute__((ext_vector_type(4)));
typedef unsigned short u16;

// Zero cnt: 64 KB = 4096 int4, 16 blocks x 256 threads.
__global__ __launch_bounds__(256) void zero_k(int4* __restrict__ p) {
  p[blockIdx.x * 256 + threadIdx.x] = int4{0, 0, 0, 0};
}

// K1: blocks [0,512): y(bf16), z(f32) = x @ [W|B]^T via bf16 MFMA, K=128.
//     GEMM staging is software-pipelined: kc+1's 9 float4 loads are issued
//     before kc's MFMA phase, so global latency hides under compute (r16
//     counters: VALUBusy 2.2% => staging chain was serial).
//     blocks [512,768): edge append (dups kept), 3-phase ILP atomics (r14 lesson).
__global__ __launch_bounds__(256, 2) void k1(const float* __restrict__ x,
                                             const int* __restrict__ ei,
                                             const float* __restrict__ W,
                                             const float* __restrict__ Bm,
                                             __bf16* __restrict__ y,
                                             float* __restrict__ z,
                                             int* __restrict__ cnt,
                                             u16* __restrict__ slab) {
  __shared__ __bf16 sA[32][40];    // 2.5 KB
  __shared__ __bf16 sB[256][40];   // 20 KB  (rows 0..127 = W, 128..255 = B)
  __shared__ int s_any;
  int b = blockIdx.x, t = threadIdx.x;

  if (b < GEMMB) {
    int l = t & 63, wid = t >> 6;
    int g = l >> 4, ln = l & 15;
    int mh = wid & 1, nh = wid >> 1;
    int row0 = b * 32;

    int arr = t >> 3, aq = t & 7;               // A-stage coords (per thread)
    const float* arow = &x[(size_t)(row0 + arr) * D + aq * 4];
    int brr[8], bq[8];
    const float* brow[8];
#pragma unroll
    for (int u = 0; u < 8; ++u) {               // B'-stage coords
      int f = u * 256 + t;
      brr[u] = f >> 3; bq[u] = f & 7;
      brow[u] = (brr[u] < 128) ? &W[(size_t)brr[u] * D + bq[u] * 4]
                               : &Bm[(size_t)(brr[u] - 128) * D + bq[u] * 4];
    }

    f32x4 acc[8];
#pragma unroll
    for (int nb = 0; nb < 8; ++nb) acc[nb] = f32x4{0.f, 0.f, 0.f, 0.f};

    // prologue: stage kc=0
    float4 pa = *(const float4*)arow;
    float4 pb[8];
#pragma unroll
    for (int u = 0; u < 8; ++u) pb[u] = *(const float4*)(brow[u]);
    {
      bf16x4 wa = {(__bf16)pa.x, (__bf16)pa.y, (__bf16)pa.z, (__bf16)pa.w};
      *(bf16x4*)&sA[arr][aq * 4] = wa;
#pragma unroll
      for (int u = 0; u < 8; ++u) {
        bf16x4 wb = {(__bf16)pb[u].x, (__bf16)pb[u].y, (__bf16)pb[u].z, (__bf16)pb[u].w};
        *(bf16x4*)&sB[brr[u]][bq[u] * 4] = wb;
      }
    }
    __syncthreads();

#pragma unroll
    for (int kc = 0; kc < 4; ++kc) {
      // issue next-stage loads early: in flight during this stage's MFMAs
      float4 na; float4 nb_[8];
      if (kc < 3) {
        na = *(const float4*)(arow + (kc + 1) * 32);
#pragma unroll
        for (int u = 0; u < 8; ++u) nb_[u] = *(const float4*)(brow[u] + (kc + 1) * 32);
      }
      bf16x8 afr = *(const bf16x8*)&sA[mh * 16 + ln][g * 8];
#pragma unroll
      for (int nb = 0; nb < 8; ++nb) {
        bf16x8 bfr = *(const bf16x8*)&sB[nh * 128 + nb * 16 + ln][g * 8];
        acc[nb] = __builtin_amdgcn_mfma_f32_16x16x32_bf16(afr, bfr, acc[nb], 0, 0, 0);
      }
      if (kc < 3) {
        __syncthreads();                       // all LDS reads of stage kc done
        bf16x4 wa = {(__bf16)na.x, (__bf16)na.y, (__bf16)na.z, (__bf16)na.w};
        *(bf16x4*)&sA[arr][aq * 4] = wa;
#pragma unroll
        for (int u = 0; u < 8; ++u) {
          bf16x4 wb = {(__bf16)nb_[u].x, (__bf16)nb_[u].y, (__bf16)nb_[u].z, (__bf16)nb_[u].w};
          *(bf16x4*)&sB[brr[u]][bq[u] * 4] = wb;
        }
        __syncthreads();                       // stage kc+1 visible
      }
    }
    // C/D: col = ln, row = g*4+i [verified r4-r9]; nh=0 -> y (bf16), nh=1 -> z (f32)
    if (nh == 0) {
#pragma unroll
      for (int nb = 0; nb < 8; ++nb)
#pragma unroll
        for (int i = 0; i < 4; ++i)
          y[(size_t)(row0 + mh * 16 + g * 4 + i) * D + nb * 16 + ln] = (__bf16)acc[nb][i];
    } else {
#pragma unroll
      for (int nb = 0; nb < 8; ++nb)
#pragma unroll
        for (int i = 0; i < 4; ++i)
          z[(size_t)(row0 + mh * 16 + g * 4 + i) * D + nb * 16 + ln] = acc[nb][i];
    }
  } else {
    // edge pass: per-block width detect (int64 => odd int32 words all zero)
    if (t == 0) s_any = 0;
    __syncthreads();
    int base = (b - GEMMB) * 2048;
    int any = 0;
#pragma unroll
    for (int u = 0; u < 8; ++u) any |= ei[2 * (base + u * 256 + t) + 1];
    if (any) atomicOr(&s_any, 1);
    __syncthreads();
    int is32 = s_any;
    int s_[8], d_[8], slot_[8];
#pragma unroll
    for (int u = 0; u < 8; ++u) {        // phase 1: load all
      int i = base + u * 256 + t;
      s_[u] = is32 ? ei[i] : ei[2 * i];
      d_[u] = is32 ? ei[NE + i] : ei[2 * (NE + i)];
    }
#pragma unroll
    for (int u = 0; u < 8; ++u)          // phase 2: all atomics in flight
      slot_[u] = atomicAdd(&cnt[d_[u]], 1);
#pragma unroll
    for (int u = 0; u < 8; ++u)          // phase 3: stores
      if (slot_[u] < CAP) slab[((size_t)d_[u] << 7) + slot_[u]] = (u16)s_[u];
  }
}

// K2: out[row] = (1/max(uniq,1)) * sum_{unique src} y_bf16[src] + z[row].
// One row per 32-lane group; LDS-bitmap dedup; z-load hoisted above the
// front-end so its latency hides under dedup.
#define RPB 8
__global__ __launch_bounds__(256) void gather_k(const int* __restrict__ cnt,
                                                const u16* __restrict__ slab,
                                                const u16* __restrict__ y,
                                                const float* __restrict__ z,
                                                float* __restrict__ out) {
  __shared__ u16 s_col[RPB][CAP];        // 2 KB
  __shared__ unsigned s_bm[RPB][512];    // 16 KB
  int t = threadIdx.x, lane = t & 31, r = t >> 5;
  int row = blockIdx.x * RPB + r;
  float4 zv = *(const float4*)(z + (size_t)row * D + lane * 4);  // hoisted
  int k = cnt[row];
  if (k > CAP) k = CAP;
  const u16* srow = slab + ((size_t)row << 7);
  for (int j = lane; j < k; j += 32) s_col[r][j] = srow[j];
#pragma unroll
  for (int u = 0; u < 16; ++u) s_bm[r][u * 32 + lane] = 0u;

  int lu = 0;
  for (int j = lane; j < k; j += 32) {
    unsigned c = s_col[r][j];
    unsigned bit = 1u << (c & 31);
    unsigned old = atomicOr(&s_bm[r][c >> 5], bit);
    int kp = (old & bit) ? 0 : 1;
    s_col[r][j] = (u16)(c | (kp << 15));
    lu += kp;
  }
#pragma unroll
  for (int off = 16; off; off >>= 1) lu += __shfl_xor(lu, off);
  float dinv = 1.0f / (float)(lu > 0 ? lu : 1);

  float4 a[8];
#pragma unroll
  for (int u = 0; u < 8; ++u) a[u] = float4{0.f, 0.f, 0.f, 0.f};
  const u16* yl = y + lane * 4;          // 4 bf16 features per lane
#define ACCB(aa, vv, ff)                                                  \
  { aa.x += ff * __uint_as_float((vv).x << 16);                           \
    aa.y += ff * __uint_as_float((vv).x & 0xffff0000u);                   \
    aa.z += ff * __uint_as_float((vv).y << 16);                           \
    aa.w += ff * __uint_as_float((vv).y & 0xffff0000u); }
  int j = 0;
  for (; j + 8 <= k; j += 8) {
    float f[8];
    uint2 v[8];
#pragma unroll
    for (int u = 0; u < 8; ++u) {
      int cc = s_col[r][j + u];
      f[u] = (cc >> 15) ? 1.0f : 0.0f;
      v[u] = *(const uint2*)(yl + (size_t)(cc & 0x3FFF) * D);
    }
#pragma unroll
    for (int u = 0; u < 8; ++u) ACCB(a[u], v[u], f[u])
  }
  for (; j < k; ++j) {
    int cc = s_col[r][j];
    float f0 = (cc >> 15) ? 1.0f : 0.0f;
    uint2 v0 = *(const uint2*)(yl + (size_t)(cc & 0x3FFF) * D);
    ACCB(a[0], v0, f0)
  }
#undef ACCB
#pragma unroll
  for (int u = 4; u < 8; ++u) {
    a[u - 4].x += a[u].x; a[u - 4].y += a[u].y;
    a[u - 4].z += a[u].z; a[u - 4].w += a[u].w;
  }
  float4 o;
  o.x = (a[0].x + a[1].x + a[2].x + a[3].x) * dinv + zv.x;
  o.y = (a[0].y + a[1].y + a[2].y + a[3].y) * dinv + zv.y;
  o.z = (a[0].z + a[1].z + a[2].z + a[3].z) * dinv + zv.z;
  o.w = (a[0].w + a[1].w + a[2].w + a[3].w) * dinv + zv.w;
  *(float4*)(out + (size_t)row * D + lane * 4) = o;
}

extern "C" void kernel_launch(void* const* d_in, const int* in_sizes, int n_in,
                              void* d_out, int out_size, void* d_ws, size_t ws_size,
                              hipStream_t stream) {
  const float* x = (const float*)d_in[0];
  const int* ei = (const int*)d_in[1];
  const float* W = (const float*)d_in[2];
  const float* Bm = (const float*)d_in[3];
  float* out = (float*)d_out;
  char* ws = (char*)d_ws;
  int* cnt = (int*)(ws + OFF_CNT);
  u16* slab = (u16*)(ws + OFF_SLAB);
  __bf16* y = (__bf16*)(ws + OFF_Y);
  float* z = (float*)(ws + OFF_Z);

  zero_k<<<16, 256, 0, stream>>>((int4*)ws);               // cnt only, 64 KB
  k1<<<GEMMB + FILLB, 256, 0, stream>>>(x, ei, W, Bm, y, z, cnt, slab);
  gather_k<<<NN / RPB, 256, 0, stream>>>(cnt, slab, (const u16*)y, z, out);
}

// Round 18
// 58.343 us; speedup vs baseline: 1.7041x; 1.0114x over previous
//
#include <hip/hip_runtime.h>

#define NN  16384
#define NE  524288
#define D   128
#define CAP 128     // raw in-degree max ~63 (Poisson 32 over 16384 draws)

// ws layout (bytes); total ~21.1 MB (ws evidenced ~260 MB)
#define OFF_CNT  0u          // int[16384] raw in-degree (dups included)
#define OFF_SLAB 65536u      // u16[16384*128] = 4 MB src ids per dst (dups included)
#define OFF_Y    4259840u    // __bf16[16384*128] = 4 MB   y = x @ W^T (bf16)
#define OFF_Z    8454144u    // float[16384*128] = 8 MB    z = x @ B^T
#define OFF_XB   16842752u   // __bf16[16384*128] = 4 MB   x in bf16
#define OFF_WB   21037056u   // __bf16[256*128] = 64 KB    [W;B] in bf16

typedef __bf16 bf16x4 __attribute__((ext_vector_type(4)));
typedef __bf16 bf16x8 __attribute__((ext_vector_type(8)));
typedef float  f32x4  __attribute__((ext_vector_type(4)));
typedef unsigned short u16;

// prep: blocks [0,16) zero cnt; [16,48) convert [W;B] -> wbg bf16;
//       [48,2096) convert x -> xb bf16. Same per-element f32->bf16 rounding
//       k1 used to do inline, hoisted out of the hot kernel.
__global__ __launch_bounds__(256) void prep_k(const float* __restrict__ x,
                                              const float* __restrict__ W,
                                              const float* __restrict__ Bm,
                                              __bf16* __restrict__ xb,
                                              __bf16* __restrict__ wbg,
                                              int4* __restrict__ cnt4) {
  int b = blockIdx.x, t = threadIdx.x;
  if (b < 16) {
    cnt4[b * 256 + t] = int4{0, 0, 0, 0};
  } else if (b < 48) {
    int i = (b - 16) * 256 + t;          // 8192 float4 = W(4096) then B(4096)
    float4 v = (i < 4096) ? ((const float4*)W)[i] : ((const float4*)Bm)[i - 4096];
    bf16x4 w = {(__bf16)v.x, (__bf16)v.y, (__bf16)v.z, (__bf16)v.w};
    ((bf16x4*)wbg)[i] = w;
  } else {
    int i = (b - 48) * 256 + t;          // 524288 float4 of x
    float4 v = ((const float4*)x)[i];
    bf16x4 w = {(__bf16)v.x, (__bf16)v.y, (__bf16)v.z, (__bf16)v.w};
    ((bf16x4*)xb)[i] = w;
  }
}

// K1: blocks [0,256): y(bf16), z(f32) = xb @ [W|B]^T, BM=64, 4 waves.
//     Whole bf16 [W;B] staged to LDS once (68 KB, +16B pad => 2-way banks);
//     kc loop: 1 global 16B A-load + 16 LDS b128 reads + 16 MFMAs, NO barriers.
//     blocks [256,512): edge append (dups kept), 3-phase ILP atomics.
__global__ __launch_bounds__(256, 2) void k1(const u16* __restrict__ xb,
                                             const u16* __restrict__ wbg,
                                             const int* __restrict__ ei,
                                             __bf16* __restrict__ y,
                                             float* __restrict__ z,
                                             int* __restrict__ cnt,
                                             u16* __restrict__ slab) {
  __shared__ __align__(16) __bf16 swb[256][136];   // 68 KB, 272B row stride
  __shared__ int s_any;
  int b = blockIdx.x, t = threadIdx.x;

  if (b < 256) {
    int l = t & 63, wid = t >> 6;
    int g = l >> 4, ln = l & 15;
    int row0 = b * 64;

    // stage [W;B] bf16: 4096 uint4, 16 per thread, coalesced
#pragma unroll
    for (int u = 0; u < 16; ++u) {
      int e = u * 256 + t;
      int rr = e >> 4, q = e & 15;
      uint4 v = ((const uint4*)wbg)[e];
      *(uint4*)&swb[rr][q * 8] = v;
    }
    __syncthreads();   // the only barrier

    f32x4 accY[8], accZ[8];
#pragma unroll
    for (int nb = 0; nb < 8; ++nb) {
      accY[nb] = f32x4{0.f, 0.f, 0.f, 0.f};
      accZ[nb] = f32x4{0.f, 0.f, 0.f, 0.f};
    }
    const u16* xrow = xb + (size_t)(row0 + wid * 16 + ln) * D;

#pragma unroll
    for (int kc = 0; kc < 4; ++kc) {
      bf16x8 afr = *(const bf16x8*)(xrow + kc * 32 + g * 8);
#pragma unroll
      for (int nb = 0; nb < 8; ++nb) {
        bf16x8 bw = *(const bf16x8*)&swb[nb * 16 + ln][kc * 32 + g * 8];
        accY[nb] = __builtin_amdgcn_mfma_f32_16x16x32_bf16(afr, bw, accY[nb], 0, 0, 0);
        bf16x8 bb = *(const bf16x8*)&swb[128 + nb * 16 + ln][kc * 32 + g * 8];
        accZ[nb] = __builtin_amdgcn_mfma_f32_16x16x32_bf16(afr, bb, accZ[nb], 0, 0, 0);
      }
    }
    // C/D: col = ln, row = g*4+i [verified r4-r17]
#pragma unroll
    for (int nb = 0; nb < 8; ++nb)
#pragma unroll
      for (int i = 0; i < 4; ++i) {
        size_t orow = (size_t)(row0 + wid * 16 + g * 4 + i) * D + nb * 16 + ln;
        y[orow] = (__bf16)accY[nb][i];
        z[orow] = accZ[nb][i];
      }
  } else {
    // edge pass: per-block width detect (int64 => odd int32 words all zero)
    if (t == 0) s_any = 0;
    __syncthreads();
    int base = (b - 256) * 2048;
    int any = 0;
#pragma unroll
    for (int u = 0; u < 8; ++u) any |= ei[2 * (base + u * 256 + t) + 1];
    if (any) atomicOr(&s_any, 1);
    __syncthreads();
    int is32 = s_any;
    int s_[8], d_[8], slot_[8];
#pragma unroll
    for (int u = 0; u < 8; ++u) {        // phase 1: load all
      int i = base + u * 256 + t;
      s_[u] = is32 ? ei[i] : ei[2 * i];
      d_[u] = is32 ? ei[NE + i] : ei[2 * (NE + i)];
    }
#pragma unroll
    for (int u = 0; u < 8; ++u)          // phase 2: all atomics in flight
      slot_[u] = atomicAdd(&cnt[d_[u]], 1);
#pragma unroll
    for (int u = 0; u < 8; ++u)          // phase 3: stores
      if (slot_[u] < CAP) slab[((size_t)d_[u] << 7) + slot_[u]] = (u16)s_[u];
  }
}

// K2: out[row] = (1/max(uniq,1)) * sum_{unique src} y_bf16[src] + z[row].
// One row per 32-lane group; LDS-bitmap dedup; z-load hoisted.
#define RPB 8
__global__ __launch_bounds__(256) void gather_k(const int* __restrict__ cnt,
                                                const u16* __restrict__ slab,
                                                const u16* __restrict__ y,
                                                const float* __restrict__ z,
                                                float* __restrict__ out) {
  __shared__ u16 s_col[RPB][CAP];        // 2 KB
  __shared__ unsigned s_bm[RPB][512];    // 16 KB
  int t = threadIdx.x, lane = t & 31, r = t >> 5;
  int row = blockIdx.x * RPB + r;
  float4 zv = *(const float4*)(z + (size_t)row * D + lane * 4);  // hoisted
  int k = cnt[row];
  if (k > CAP) k = CAP;
  const u16* srow = slab + ((size_t)row << 7);
  for (int j = lane; j < k; j += 32) s_col[r][j] = srow[j];
#pragma unroll
  for (int u = 0; u < 16; ++u) s_bm[r][u * 32 + lane] = 0u;

  int lu = 0;
  for (int j = lane; j < k; j += 32) {
    unsigned c = s_col[r][j];
    unsigned bit = 1u << (c & 31);
    unsigned old = atomicOr(&s_bm[r][c >> 5], bit);
    int kp = (old & bit) ? 0 : 1;
    s_col[r][j] = (u16)(c | (kp << 15));
    lu += kp;
  }
#pragma unroll
  for (int off = 16; off; off >>= 1) lu += __shfl_xor(lu, off);
  float dinv = 1.0f / (float)(lu > 0 ? lu : 1);

  float4 a[8];
#pragma unroll
  for (int u = 0; u < 8; ++u) a[u] = float4{0.f, 0.f, 0.f, 0.f};
  const u16* yl = y + lane * 4;          // 4 bf16 features per lane
#define ACCB(aa, vv, ff)                                                  \
  { aa.x += ff * __uint_as_float((vv).x << 16);                           \
    aa.y += ff * __uint_as_float((vv).x & 0xffff0000u);                   \
    aa.z += ff * __uint_as_float((vv).y << 16);                           \
    aa.w += ff * __uint_as_float((vv).y & 0xffff0000u); }
  int j = 0;
  for (; j + 8 <= k; j += 8) {
    float f[8];
    uint2 v[8];
#pragma unroll
    for (int u = 0; u < 8; ++u) {
      int cc = s_col[r][j + u];
      f[u] = (cc >> 15) ? 1.0f : 0.0f;
      v[u] = *(const uint2*)(yl + (size_t)(cc & 0x3FFF) * D);
    }
#pragma unroll
    for (int u = 0; u < 8; ++u) ACCB(a[u], v[u], f[u])
  }
  for (; j < k; ++j) {
    int cc = s_col[r][j];
    float f0 = (cc >> 15) ? 1.0f : 0.0f;
    uint2 v0 = *(const uint2*)(yl + (size_t)(cc & 0x3FFF) * D);
    ACCB(a[0], v0, f0)
  }
#undef ACCB
#pragma unroll
  for (int u = 4; u < 8; ++u) {
    a[u - 4].x += a[u].x; a[u - 4].y += a[u].y;
    a[u - 4].z += a[u].z; a[u - 4].w += a[u].w;
  }
  float4 o;
  o.x = (a[0].x + a[1].x + a[2].x + a[3].x) * dinv + zv.x;
  o.y = (a[0].y + a[1].y + a[2].y + a[3].y) * dinv + zv.y;
  o.z = (a[0].z + a[1].z + a[2].z + a[3].z) * dinv + zv.z;
  o.w = (a[0].w + a[1].w + a[2].w + a[3].w) * dinv + zv.w;
  *(float4*)(out + (size_t)row * D + lane * 4) = o;
}

extern "C" void kernel_launch(void* const* d_in, const int* in_sizes, int n_in,
                              void* d_out, int out_size, void* d_ws, size_t ws_size,
                              hipStream_t stream) {
  const float* x = (const float*)d_in[0];
  const int* ei = (const int*)d_in[1];
  const float* W = (const float*)d_in[2];
  const float* Bm = (const float*)d_in[3];
  float* out = (float*)d_out;
  char* ws = (char*)d_ws;
  int* cnt = (int*)(ws + OFF_CNT);
  u16* slab = (u16*)(ws + OFF_SLAB);
  __bf16* y = (__bf16*)(ws + OFF_Y);
  float* z = (float*)(ws + OFF_Z);
  __bf16* xb = (__bf16*)(ws + OFF_XB);
  __bf16* wbg = (__bf16*)(ws + OFF_WB);

  prep_k<<<2096, 256, 0, stream>>>(x, W, Bm, xb, wbg, (int4*)cnt);
  k1<<<512, 256, 0, stream>>>((const u16*)xb, (const u16*)wbg, ei, y, z, cnt, slab);
  gather_k<<<NN / RPB, 256, 0, stream>>>(cnt, slab, (const u16*)y, z, out);
}